// Round 5
// baseline (35.572 us; speedup 1.0000x reference)
//
#include <hip/hip_runtime.h>
#include <hip/hip_bf16.h>

// CP tensorized embedding gather via MFMA, one-shot waves, 2 tiles/wave:
// out[t, e] = sum_r w[t,r] * B[r,e]
//   w[t,r] = U0[a,r]*U1[b,r]*U2[c,r], idx=x[t], a=idx/5000, b=(idx/50)%100, c=idx%50
//   B[r,e] = V0[e>>4,r]*V1[e&15,r]
// Wave = 32 tokens: ALL loads issued up front (x + 12 float4 U-gathers,
// independent), one wait, 16 MFMAs, burst of 16 dwordx4 stores, retire.
// No store->load vmcnt serialization anywhere. Floor = 105 MB output (~16 us).

#define RANKK 32
#define EMB 128

typedef __attribute__((ext_vector_type(8))) short short8v;  // 8 bf16 = 4 VGPRs
typedef __attribute__((ext_vector_type(4))) float f32x4;

__device__ __forceinline__ short f2bf(float f) {
    union { __hip_bfloat16 h; short s; } u;
    u.h = __float2bfloat16(f);   // RNE
    return u.s;
}

__global__ __launch_bounds__(256) void cpemb_mfma(
    const int* __restrict__ x,
    const float* __restrict__ U0, const float* __restrict__ U1,
    const float* __restrict__ U2,
    const float* __restrict__ V0, const float* __restrict__ V1,
    float* __restrict__ out, int ntok)
{
    const int tid  = threadIdx.x;
    const int lane = tid & 63;
    const int grp  = blockIdx.x * 4 + (tid >> 6);   // one 32-token group/wave
    const int t0   = grp << 5;
    if (t0 >= ntok) return;

    const int t_l = lane & 15;   // token-within-tile; D col
    const int g   = lane >> 4;   // k-chunk group; D row block (g*4+j)
    const int rb  = g * 8;       // rank base (k = rb..rb+7)

    // ---- issue BOTH token-index loads first (head of dependent chain)
    int tok0 = t0 + t_l, tok1 = t0 + 16 + t_l;
    const bool ok0 = tok0 < ntok, ok1 = tok1 < ntok;
    if (!ok0) tok0 = ntok - 1;
    if (!ok1) tok1 = ntok - 1;
    const unsigned ui0 = (unsigned)x[tok0];
    const unsigned ui1 = (unsigned)x[tok1];

    // ---- decode + issue all 12 U-gathers (independent, L1-resident tables)
    const unsigned a0i   = ui0 / 5000u;
    const unsigned rem0  = ui0 - a0i * 5000u;
    const unsigned b0i   = rem0 / 50u;
    const unsigned c0i   = rem0 - b0i * 50u;
    const unsigned a1i   = ui1 / 5000u;
    const unsigned rem1  = ui1 - a1i * 5000u;
    const unsigned b1i   = rem1 / 50u;
    const unsigned c1i   = rem1 - b1i * 50u;

    const float4* q00 = (const float4*)(U0 + a0i * RANKK + rb);
    const float4* q01 = (const float4*)(U1 + b0i * RANKK + rb);
    const float4* q02 = (const float4*)(U2 + c0i * RANKK + rb);
    const float4* q10 = (const float4*)(U0 + a1i * RANKK + rb);
    const float4* q11 = (const float4*)(U1 + b1i * RANKK + rb);
    const float4* q12 = (const float4*)(U2 + c1i * RANKK + rb);
    float4 ua0 = q00[0], ua1 = q00[1];
    float4 ub0 = q01[0], ub1 = q01[1];
    float4 uc0 = q02[0], uc1 = q02[1];
    float4 va0 = q10[0], va1 = q10[1];
    float4 vb0 = q11[0], vb1 = q11[1];
    float4 vc0 = q12[0], vc1 = q12[1];

    // ---- table fragments (MFMA A operand): V1 row = t_l, V0 row = eb
    float v1r[8];
    {
        const float4* p = (const float4*)(V1 + t_l * RANKK + rb);
        float4 lo = p[0], hi = p[1];
        v1r[0]=lo.x; v1r[1]=lo.y; v1r[2]=lo.z; v1r[3]=lo.w;
        v1r[4]=hi.x; v1r[5]=hi.y; v1r[6]=hi.z; v1r[7]=hi.w;
    }
    short8v bfrag[8];
    #pragma unroll
    for (int eb = 0; eb < 8; ++eb) {
        const float4* p = (const float4*)(V0 + eb * RANKK + rb);
        float4 lo = p[0], hi = p[1];
        float v0r[8] = {lo.x, lo.y, lo.z, lo.w, hi.x, hi.y, hi.z, hi.w};
        #pragma unroll
        for (int i = 0; i < 8; ++i)
            bfrag[eb][i] = f2bf(v0r[i] * v1r[i]);
    }

    // ---- W-fragments for both tiles
    short8v afrag0, afrag1;
    {
        float wv[8];
        wv[0]=ua0.x*ub0.x*uc0.x; wv[1]=ua0.y*ub0.y*uc0.y;
        wv[2]=ua0.z*ub0.z*uc0.z; wv[3]=ua0.w*ub0.w*uc0.w;
        wv[4]=ua1.x*ub1.x*uc1.x; wv[5]=ua1.y*ub1.y*uc1.y;
        wv[6]=ua1.z*ub1.z*uc1.z; wv[7]=ua1.w*ub1.w*uc1.w;
        #pragma unroll
        for (int i = 0; i < 8; ++i) afrag0[i] = f2bf(wv[i]);
    }
    {
        float wv[8];
        wv[0]=va0.x*vb0.x*vc0.x; wv[1]=va0.y*vb0.y*vc0.y;
        wv[2]=va0.z*vb0.z*vc0.z; wv[3]=va0.w*vb0.w*vc0.w;
        wv[4]=va1.x*vb1.x*vc1.x; wv[5]=va1.y*vb1.y*vc1.y;
        wv[6]=va1.z*vb1.z*vc1.z; wv[7]=va1.w*vb1.w*vc1.w;
        #pragma unroll
        for (int i = 0; i < 8; ++i) afrag1[i] = f2bf(wv[i]);
    }

    // ---- 16 MFMAs, then 16 independent dwordx4 stores (burst, then retire)
    // lane holds token = tile_t0 + t_l, e = eb*16 + g*4 + j (j contiguous)
    f32x4 acc0[8], acc1[8];
    #pragma unroll
    for (int eb = 0; eb < 8; ++eb) {
        f32x4 z = {0.f, 0.f, 0.f, 0.f};
        acc0[eb] = __builtin_amdgcn_mfma_f32_16x16x32_bf16(bfrag[eb], afrag0, z, 0, 0, 0);
        acc1[eb] = __builtin_amdgcn_mfma_f32_16x16x32_bf16(bfrag[eb], afrag1, z, 0, 0, 0);
    }

    float* orow0 = out + (size_t)(t0 + t_l) * EMB + g * 4;
    float* orow1 = out + (size_t)(t0 + 16 + t_l) * EMB + g * 4;
    #pragma unroll
    for (int eb = 0; eb < 8; ++eb) {
        if (ok0) {
            float4 v = make_float4(acc0[eb][0], acc0[eb][1], acc0[eb][2], acc0[eb][3]);
            *(float4*)(orow0 + eb * 16) = v;
        }
        if (ok1) {
            float4 v = make_float4(acc1[eb][0], acc1[eb][1], acc1[eb][2], acc1[eb][3]);
            *(float4*)(orow1 + eb * 16) = v;
        }
    }
}

extern "C" void kernel_launch(void* const* d_in, const int* in_sizes, int n_in,
                              void* d_out, int out_size, void* d_ws, size_t ws_size,
                              hipStream_t stream) {
    const int*   x  = (const int*)d_in[0];
    const float* U0 = (const float*)d_in[1];
    const float* U1 = (const float*)d_in[2];
    const float* U2 = (const float*)d_in[3];
    const float* V0 = (const float*)d_in[4];
    const float* V1 = (const float*)d_in[5];
    float* out = (float*)d_out;

    const int ntok    = in_sizes[0];            // 204800
    const int ngroups = (ntok + 31) >> 5;       // 6400 (32 tokens/wave)
    const int blocks  = (ngroups + 3) >> 2;     // 1600 blocks, 4 waves each

    cpemb_mfma<<<blocks, 256, 0, stream>>>(x, U0, U1, U2, V0, V1, out, ntok);
}